// Round 11
// baseline (143.617 us; speedup 1.0000x reference)
//
#include <hip/hip_runtime.h>
#include <hip/hip_bf16.h>

#define VOCAB 200000
#define EDIM  256
#define NTILES 12800            // 204800 rows / 16
#define GRID   512              // persistent blocks, 2 per CU
#define ITERS  25               // NTILES / GRID
#define DEPTH  4                // LDS A-buffer ring

typedef __attribute__((ext_vector_type(4))) float  f32x4;
typedef __attribute__((ext_vector_type(4))) int    i32x4;
typedef __attribute__((ext_vector_type(8))) __bf16 bf16x8;

typedef const __attribute__((address_space(1))) unsigned int* gas_u32p;
typedef __attribute__((address_space(3))) unsigned int* las_u32p;

__device__ __forceinline__ __bf16 f2bf(float f) {
    unsigned u = __builtin_bit_cast(unsigned, f);
    u += 0x7FFFu + ((u >> 16) & 1u);           // round-to-nearest-even
    unsigned short s = (unsigned short)(u >> 16);
    return __builtin_bit_cast(__bf16, s);
}

// Pack B into MFMA fragment order (verified round 1).
// k = a*16 + b;  B[k][j] = core1[b, j, a], core1 is (16,256,16).
// bpk[(kk*16 + nt)*64 + lane] : lane l elem e = B[kk*32 + (l>>4)*8 + e][nt*16 + (l&15)]
__global__ void pack_b_kernel(const float* __restrict__ core1, bf16x8* __restrict__ bpk) {
    int t    = blockIdx.x * 256 + threadIdx.x;   // 0..8191
    int lane = t & 63;
    int nt   = (t >> 6) & 15;
    int kk   = t >> 10;
    int j     = nt * 16 + (lane & 15);
    int kbase = kk * 32 + ((lane >> 4) * 8);
    bf16x8 v;
#pragma unroll
    for (int e = 0; e < 8; ++e) {
        int k = kbase + e;
        int b = k & 15, a = k >> 4;
        v[e] = f2bf(core1[(b * 256 + j) * 16 + a]);
    }
    bpk[t] = v;
}

// Repack A: core0 (16, VOCAB, 16) f32  ->  abf[v][k] bf16, k = a*16 + b.
// Thread t: v = t>>4, a = t&15. Reads 64 B contiguous (16-stream sequential
// across the wave); writes 32 B at byte v*512 + a*32 -> wave writes one
// contiguous 2 KB chunk (perfectly coalesced). RNE via v_cvt_pk_bf16_f32.
__global__ __launch_bounds__(256) void repack_a_kernel(const float* __restrict__ core0,
                                                       char* __restrict__ abf) {
    int t = blockIdx.x * 256 + threadIdx.x;     // 0 .. VOCAB*16-1
    int v = t >> 4, a = t & 15;
    const float* src = core0 + ((long)a * VOCAB + v) * 16;
    f32x4 s0 = *(const f32x4*)(src);
    f32x4 s1 = *(const f32x4*)(src + 4);
    f32x4 s2 = *(const f32x4*)(src + 8);
    f32x4 s3 = *(const f32x4*)(src + 12);
    int p[8];
    asm("v_cvt_pk_bf16_f32 %0, %1, %2" : "=v"(p[0]) : "v"(s0[0]), "v"(s0[1]));
    asm("v_cvt_pk_bf16_f32 %0, %1, %2" : "=v"(p[1]) : "v"(s0[2]), "v"(s0[3]));
    asm("v_cvt_pk_bf16_f32 %0, %1, %2" : "=v"(p[2]) : "v"(s1[0]), "v"(s1[1]));
    asm("v_cvt_pk_bf16_f32 %0, %1, %2" : "=v"(p[3]) : "v"(s1[2]), "v"(s1[3]));
    asm("v_cvt_pk_bf16_f32 %0, %1, %2" : "=v"(p[4]) : "v"(s2[0]), "v"(s2[1]));
    asm("v_cvt_pk_bf16_f32 %0, %1, %2" : "=v"(p[5]) : "v"(s2[2]), "v"(s2[3]));
    asm("v_cvt_pk_bf16_f32 %0, %1, %2" : "=v"(p[6]) : "v"(s3[0]), "v"(s3[1]));
    asm("v_cvt_pk_bf16_f32 %0, %1, %2" : "=v"(p[7]) : "v"(s3[2]), "v"(s3[3]));
    i32x4 lo = { p[0], p[1], p[2], p[3] };
    i32x4 hi = { p[4], p[5], p[6], p[7] };
    char* dst = abf + (long)v * 512 + a * 32;
    *(i32x4*)(dst)      = lo;
    *(i32x4*)(dst + 16) = hi;
}

// ---------------- bf16-gather main kernel (repack path) ----------------
// Gather one kk-slab of a 16-row tile: ONE inst/wave. Lane l = q*16+r reads
// 16 B of row idx_r at byte kk*64 + q*16 (contiguous 64 B per row). LDS dest
// linear: slot + wave*1024 + l*16; entry l = exactly lane l's af fragment.
__device__ __forceinline__ void issue_gather_bf(const char* __restrict__ abf, int idx,
                                                int wave, int q, char* slot) {
    const char* src = abf + (long)idx * 512 + wave * 64 + q * 16;
    __builtin_amdgcn_global_load_lds((gas_u32p)src, (las_u32p)(slot + wave * 1024), 16, 0, 0);
}

__global__ __launch_bounds__(512, 4) void tr_embed_bf_kernel(
        const int* __restrict__ x, const char* __restrict__ abf,
        const bf16x8* __restrict__ bpk, float* __restrict__ out) {
    __shared__ char lds[DEPTH * 8192 + ITERS * 16 * 4];   // 32 KB ring + 1.6 KB idx
    int* const sIdx = (int*)(lds + DEPTH * 8192);
    const int tid  = threadIdx.x;
    const int lane = tid & 63;
    const int wave = tid >> 6;                  // 0..7
    const int r    = lane & 15;
    const int q    = lane >> 4;

    // B panel -> registers: wave w owns nt = 2w, 2w+1
    bf16x8 B0[8], B1[8];
#pragma unroll
    for (int kk = 0; kk < 8; ++kk) {
        B0[kk] = bpk[(kk * 16 + 2 * wave)     * 64 + lane];
        B1[kk] = bpk[(kk * 16 + 2 * wave + 1) * 64 + lane];
    }

    const int b0 = blockIdx.x;

    // stage all idx values into LDS (off the vmcnt path)
    for (int j = tid; j < ITERS * 16; j += 512)
        sIdx[j] = x[(b0 + (j >> 4) * GRID) * 16 + (j & 15)];
    __syncthreads();

    // prologue: gather tiles 0..2
#pragma unroll
    for (int p = 0; p < 3; ++p)
        issue_gather_bf(abf, sIdx[p * 16 + r], wave, q, lds + p * 8192);
    asm volatile("s_waitcnt vmcnt(0)" ::: "memory");
    __builtin_amdgcn_s_barrier();

    for (int i = 0; i < ITERS; ++i) {
        const int t = b0 + i * GRID;
        char* cur = lds + (i & 3) * 8192;

        if (i + 3 < ITERS)
            issue_gather_bf(abf, sIdx[(i + 3) * 16 + r], wave, q,
                            lds + ((i + 3) & 3) * 8192);
        __builtin_amdgcn_sched_barrier(0);      // pin gather issue at iter top

        f32x4 acc0 = {}, acc1 = {};
#pragma unroll
        for (int kk = 0; kk < 8; ++kk) {
            bf16x8 af = *(const bf16x8*)(cur + kk * 1024 + lane * 16);
            acc0 = __builtin_amdgcn_mfma_f32_16x16x32_bf16(af, B0[kk], acc0, 0, 0, 0);
            acc1 = __builtin_amdgcn_mfma_f32_16x16x32_bf16(af, B1[kk], acc1, 0, 0, 0);
        }

        float* ob = out + (long)t * 16 * 256 + (q * 4) * 256 + 2 * wave * 16 + r;
#pragma unroll
        for (int e = 0; e < 4; ++e) {
            ob[e * 256]      = acc0[e];
            ob[e * 256 + 16] = acc1[e];
        }

        // per-iter vm ops: 1 gather + 8 stores. Ops issued after g(i+1) in
        // steady state = 26; tail minimum (iter 23) = 24 -> vmcnt(24)
        // guarantees own g(i+1) retired; barrier publishes all waves' data.
        asm volatile("s_waitcnt vmcnt(24)" ::: "memory");
        __builtin_amdgcn_s_barrier();
    }
}

// ---------------- fp32-gather fallback (round-9 kernel, proven) ----------------
__device__ __forceinline__ void issue_gather(const float* __restrict__ core0, int idx,
                                             int kk, char* abuf, int lane) {
    const int q = lane >> 4;
#pragma unroll
    for (int h = 0; h < 2; ++h) {
        int c = kk * 8 + q * 2 + h;
        const float* src = core0 + ((long)(c >> 2) * VOCAB + idx) * 16 + (c & 3) * 4;
        __builtin_amdgcn_global_load_lds((gas_u32p)src,
                                         (las_u32p)(abuf + kk * 2048 + h * 1024), 16, 0, 0);
    }
}

__global__ __launch_bounds__(512, 4) void tr_embed_kernel(
        const int* __restrict__ x, const float* __restrict__ core0,
        const bf16x8* __restrict__ bpk, float* __restrict__ out) {
    __shared__ char lds[DEPTH * 16384 + ITERS * 16 * 4];
    int* const sIdx = (int*)(lds + DEPTH * 16384);
    const int tid  = threadIdx.x;
    const int lane = tid & 63;
    const int wave = tid >> 6;
    const int r    = lane & 15;
    const int q    = lane >> 4;

    bf16x8 B0[8], B1[8];
#pragma unroll
    for (int kk = 0; kk < 8; ++kk) {
        B0[kk] = bpk[(kk * 16 + 2 * wave)     * 64 + lane];
        B1[kk] = bpk[(kk * 16 + 2 * wave + 1) * 64 + lane];
    }

    const int b0 = blockIdx.x;
    for (int j = tid; j < ITERS * 16; j += 512)
        sIdx[j] = x[(b0 + (j >> 4) * GRID) * 16 + (j & 15)];
    __syncthreads();

#pragma unroll
    for (int p = 0; p < 3; ++p)
        issue_gather(core0, sIdx[p * 16 + r], wave, lds + p * 16384, lane);
    asm volatile("s_waitcnt vmcnt(0)" ::: "memory");
    __builtin_amdgcn_s_barrier();

    for (int i = 0; i < ITERS; ++i) {
        const int t = b0 + i * GRID;
        char* cur = lds + (i & 3) * 16384;
        if (i + 3 < ITERS)
            issue_gather(core0, sIdx[(i + 3) * 16 + r], wave,
                         lds + ((i + 3) & 3) * 16384, lane);
        __builtin_amdgcn_sched_barrier(0);

        f32x4 acc0 = {}, acc1 = {};
#pragma unroll
        for (int kk = 0; kk < 8; ++kk) {
            f32x4 lo = *(const f32x4*)(cur + kk * 2048 +        lane * 16);
            f32x4 hi = *(const f32x4*)(cur + kk * 2048 + 1024 + lane * 16);
            int p0, p1, p2, p3;
            asm("v_cvt_pk_bf16_f32 %0, %1, %2" : "=v"(p0) : "v"(lo[0]), "v"(lo[1]));
            asm("v_cvt_pk_bf16_f32 %0, %1, %2" : "=v"(p1) : "v"(lo[2]), "v"(lo[3]));
            asm("v_cvt_pk_bf16_f32 %0, %1, %2" : "=v"(p2) : "v"(hi[0]), "v"(hi[1]));
            asm("v_cvt_pk_bf16_f32 %0, %1, %2" : "=v"(p3) : "v"(hi[2]), "v"(hi[3]));
            i32x4 pk = { p0, p1, p2, p3 };
            bf16x8 af = __builtin_bit_cast(bf16x8, pk);
            acc0 = __builtin_amdgcn_mfma_f32_16x16x32_bf16(af, B0[kk], acc0, 0, 0, 0);
            acc1 = __builtin_amdgcn_mfma_f32_16x16x32_bf16(af, B1[kk], acc1, 0, 0, 0);
        }

        float* ob = out + (long)t * 16 * 256 + (q * 4) * 256 + 2 * wave * 16 + r;
#pragma unroll
        for (int e = 0; e < 4; ++e) {
            ob[e * 256]      = acc0[e];
            ob[e * 256 + 16] = acc1[e];
        }
        asm volatile("s_waitcnt vmcnt(20)" ::: "memory");
        __builtin_amdgcn_s_barrier();
    }
}

extern "C" void kernel_launch(void* const* d_in, const int* in_sizes, int n_in,
                              void* d_out, int out_size, void* d_ws, size_t ws_size,
                              hipStream_t stream) {
    const int*   x     = (const int*)d_in[0];
    const float* core0 = (const float*)d_in[1];
    const float* core1 = (const float*)d_in[2];
    float* out = (float*)d_out;
    bf16x8* bpk = (bf16x8*)d_ws;                          // 128 KB
    char*   abf = (char*)d_ws + 131072;                   // 102.4 MB bf16 A-table

    const size_t WS_NEED = 131072 + (size_t)VOCAB * 512;  // 102,531,072 B

    pack_b_kernel<<<32, 256, 0, stream>>>(core1, bpk);
    if (ws_size >= WS_NEED) {
        repack_a_kernel<<<VOCAB * 16 / 256, 256, 0, stream>>>(core0, abf);
        tr_embed_bf_kernel<<<GRID, 512, 0, stream>>>(x, abf, bpk, out);
    } else {
        tr_embed_kernel<<<GRID, 512, 0, stream>>>(x, core0, bpk, out);
    }
}

// Round 13
// 112.839 us; speedup vs baseline: 1.2728x; 1.2728x over previous
//
#include <hip/hip_runtime.h>
#include <hip/hip_bf16.h>

#define VOCAB  200000
#define NTILES 12800            // 204800 rows / 16
#define GRID   512              // persistent blocks, 2 per CU
#define ITERS  25               // NTILES / GRID
#define DEPTH  3                // LDS A-buffer ring (2 tiles prefetch ahead)

typedef __attribute__((ext_vector_type(4))) float  f32x4;
typedef __attribute__((ext_vector_type(4))) int    i32x4;
typedef __attribute__((ext_vector_type(8))) __bf16 bf16x8;

typedef const __attribute__((address_space(1))) unsigned int* gas_u32p;
typedef __attribute__((address_space(3))) unsigned int* las_u32p;

__device__ __forceinline__ __bf16 f2bf(float f) {
    unsigned u = __builtin_bit_cast(unsigned, f);
    u += 0x7FFFu + ((u >> 16) & 1u);           // round-to-nearest-even
    unsigned short s = (unsigned short)(u >> 16);
    return __builtin_bit_cast(__bf16, s);
}

// Pack B into MFMA fragment order (verified round 1).
// k = a*16 + b;  B[k][j] = core1[b, j, a], core1 is (16,256,16).
// bpk[(kk*16 + nt)*64 + lane] : lane l elem e = B[kk*32 + (l>>4)*8 + e][nt*16 + (l&15)]
__global__ void pack_b_kernel(const float* __restrict__ core1, bf16x8* __restrict__ bpk) {
    int t    = blockIdx.x * 256 + threadIdx.x;   // 0..8191
    int lane = t & 63;
    int nt   = (t >> 6) & 15;
    int kk   = t >> 10;
    int j     = nt * 16 + (lane & 15);
    int kbase = kk * 32 + ((lane >> 4) * 8);
    bf16x8 v;
#pragma unroll
    for (int e = 0; e < 8; ++e) {
        int k = kbase + e;
        int b = k & 15, a = k >> 4;
        v[e] = f2bf(core1[(b * 256 + j) * 16 + a]);
    }
    bpk[t] = v;
}

// A-gather for k-slab kk of a 16-row tile into LDS buffer abuf (zero VGPR,
// proven r9). Lane l fetches chunk c = kk*8 + (l>>4)*2 + h of row idx_{l&15};
// chunk c = floats 4c..4c+3 (k = a*16+b: a = c>>2, b = (c&3)*4..+3).
// LDS image: kk*2048 + h*1024 + lane*16 -> compute ds_read_b128 contiguous.
__device__ __forceinline__ void issue_gather(const float* __restrict__ core0, int idx,
                                             int kk, char* abuf, int lane) {
    const int q = lane >> 4;
#pragma unroll
    for (int h = 0; h < 2; ++h) {
        int c = kk * 8 + q * 2 + h;
        const float* src = core0 + ((long)(c >> 2) * VOCAB + idx) * 16 + (c & 3) * 4;
        __builtin_amdgcn_global_load_lds((gas_u32p)src,
                                         (las_u32p)(abuf + kk * 2048 + h * 1024), 16, 0, 0);
    }
}

// r9 skeleton + LDS-transposed C writeback. Per iter:
//   issue g(i+2) -> compute (LDS A + reg B) -> C into swizzled LDS tile
//   -> lgkmcnt(0)+barrier -> each wave stores 2 FULL rows (1 KB contiguous
//   dwordx4 bursts; was 64B-granular) -> vmcnt(6)+barrier.
// vmcnt(6): ops issued after g(i+1) at the wait = st(i-1)[2] + g(i+2)[2]
// + st(i)[2] = 6, so vmcnt(6) always retires g(i+1) before slot (i+1)%3 is
// read. g(i+2) overwrites slot (i-1)%3 only after barrier2 of iter i-1 (all
// reads done). C-LDS swizzle: dword d of row stored at d ^ ((row&7)<<2) --
// XOR on bits 2..4 keeps 16B blocks intact (read side applies same XOR) and
// spreads the column-strided write across banks (2-way max = free).
__global__ __launch_bounds__(512, 4) void tr_embed_kernel(
        const int* __restrict__ x, const float* __restrict__ core0,
        const bf16x8* __restrict__ bpk, float* __restrict__ out) {
    __shared__ char lds[DEPTH * 16384 + 16384 + ITERS * 16 * 4];  // A-ring | C-tile | idx
    char* const ldsA = lds;
    char* const ldsC = lds + DEPTH * 16384;
    int*  const sIdx = (int*)(lds + DEPTH * 16384 + 16384);
    const int tid  = threadIdx.x;
    const int lane = tid & 63;
    const int wave = tid >> 6;                  // 0..7
    const int r    = lane & 15;
    const int q    = lane >> 4;

    // B panel -> registers: wave w owns nt = 2w, 2w+1 (proven r9)
    bf16x8 B0[8], B1[8];
#pragma unroll
    for (int kk = 0; kk < 8; ++kk) {
        B0[kk] = bpk[(kk * 16 + 2 * wave)     * 64 + lane];
        B1[kk] = bpk[(kk * 16 + 2 * wave + 1) * 64 + lane];
    }

    const int b0 = blockIdx.x;

    // stage all idx values into LDS (off the vmcnt path; proven r9)
    for (int j = tid; j < ITERS * 16; j += 512)
        sIdx[j] = x[(b0 + (j >> 4) * GRID) * 16 + (j & 15)];
    __syncthreads();

    // prologue: gather tiles 0,1 into ring slots 0,1; full drain
#pragma unroll
    for (int p = 0; p < 2; ++p)
        issue_gather(core0, sIdx[p * 16 + r], wave, ldsA + p * 16384, lane);
    asm volatile("s_waitcnt vmcnt(0)" ::: "memory");
    __builtin_amdgcn_s_barrier();
    __builtin_amdgcn_sched_barrier(0);

    int slot = 0;
    for (int i = 0; i < ITERS; ++i) {
        const int t = b0 + i * GRID;
        char* cur = ldsA + slot * 16384;

        // issue gathers for tile i+2 into ring slot (slot+2)%3
        if (i + 2 < ITERS) {
            int ns = slot + 2; if (ns >= DEPTH) ns -= DEPTH;
            issue_gather(core0, sIdx[(i + 2) * 16 + r], wave, ldsA + ns * 16384, lane);
        }
        __builtin_amdgcn_sched_barrier(0);      // pin gather issue at iter top

        // ---- compute 16 rows x 32 cols per wave (LDS A + reg B) ----
        f32x4 acc0 = {}, acc1 = {};
#pragma unroll
        for (int kk = 0; kk < 8; ++kk) {
            f32x4 lo = *(const f32x4*)(cur + kk * 2048 +        lane * 16);
            f32x4 hi = *(const f32x4*)(cur + kk * 2048 + 1024 + lane * 16);
            int p0, p1, p2, p3;                 // RNE packed f32->bf16
            asm("v_cvt_pk_bf16_f32 %0, %1, %2" : "=v"(p0) : "v"(lo[0]), "v"(lo[1]));
            asm("v_cvt_pk_bf16_f32 %0, %1, %2" : "=v"(p1) : "v"(lo[2]), "v"(lo[3]));
            asm("v_cvt_pk_bf16_f32 %0, %1, %2" : "=v"(p2) : "v"(hi[0]), "v"(hi[1]));
            asm("v_cvt_pk_bf16_f32 %0, %1, %2" : "=v"(p3) : "v"(hi[2]), "v"(hi[3]));
            i32x4 pk = { p0, p1, p2, p3 };
            bf16x8 af = __builtin_bit_cast(bf16x8, pk);
            acc0 = __builtin_amdgcn_mfma_f32_16x16x32_bf16(af, B0[kk], acc0, 0, 0, 0);
            acc1 = __builtin_amdgcn_mfma_f32_16x16x32_bf16(af, B1[kk], acc1, 0, 0, 0);
        }

        // ---- C -> LDS tile (row-major 16 x 256 f32, XOR-swizzled dwords) ----
        // C/D layout (verified): lane (q,r) holds rows q*4+e, cols 32w+r / +16
#pragma unroll
        for (int e = 0; e < 4; ++e) {
            int row = q * 4 + e;
            int xr  = (row & 7) << 2;
            *(float*)(ldsC + row * 1024 + (((2 * wave * 16 + r)      ^ xr) << 2)) = acc0[e];
            *(float*)(ldsC + row * 1024 + (((2 * wave * 16 + 16 + r) ^ xr) << 2)) = acc1[e];
        }
        asm volatile("s_waitcnt lgkmcnt(0)" ::: "memory");
        __builtin_amdgcn_sched_barrier(0);
        __builtin_amdgcn_s_barrier();           // barrier1: C tile visible
        __builtin_amdgcn_sched_barrier(0);

        // ---- store rows 2w, 2w+1: 1 KB contiguous per inst ----
        {
            int r0w = 2 * wave, r1w = 2 * wave + 1;
            f32x4 v0 = *(const f32x4*)(ldsC + r0w * 1024 + (((lane * 4) ^ ((r0w & 7) << 2)) << 2));
            f32x4 v1 = *(const f32x4*)(ldsC + r1w * 1024 + (((lane * 4) ^ ((r1w & 7) << 2)) << 2));
            float* ob = out + ((long)t * 16 + r0w) * 256;
            *((f32x4*)ob + lane)         = v0;
            *((f32x4*)(ob + 256) + lane) = v1;
        }

        // counted drain: retires g(i+1) (<=6 newer ops exist); stores + g(i+2)
        // stay in flight. barrier2 publishes every wave's tile-(i+1) data and
        // fences next iter's C-writes off this iter's C-reads.
        asm volatile("s_waitcnt vmcnt(6)" ::: "memory");
        __builtin_amdgcn_s_barrier();
        __builtin_amdgcn_sched_barrier(0);

        slot = (slot == DEPTH - 1) ? 0 : slot + 1;
    }
}

extern "C" void kernel_launch(void* const* d_in, const int* in_sizes, int n_in,
                              void* d_out, int out_size, void* d_ws, size_t ws_size,
                              hipStream_t stream) {
    const int*   x     = (const int*)d_in[0];
    const float* core0 = (const float*)d_in[1];
    const float* core1 = (const float*)d_in[2];
    float* out = (float*)d_out;
    bf16x8* bpk = (bf16x8*)d_ws;                // 128 KB scratch

    pack_b_kernel<<<32, 256, 0, stream>>>(core1, bpk);
    tr_embed_kernel<<<GRID, 512, 0, stream>>>(x, core0, bpk, out);
}